// Round 7
// baseline (56.956 us; speedup 1.0000x reference)
//
#include <hip/hip_runtime.h>
#include <hip/hip_bf16.h>
#include <math.h>

// DiscriminationLoss via MFMA (R7):
//   S[k,c] = sum_{p: label[p]=k} pred[c,p],  N[k] = |{p: label[p]=k}|, k=1..32
//   A[k]   = N[k] * sum_c S[k,c]^2
//   L      = sum_{i<j} log(max(3 - sqrt(A_i + A_j), 0)^2 + 1);  out = L*(K-1)/K
//
//   D[32 seg x 32 col] += onehot(labels)[32 x 16 px] * B[16 px x 32]
//   B cols 0..7 = pred channels (bf16), col 8 = 1.0 (counts), cols 9..31 = 0.
//
// R6 lessons: (1) slab-transposed partials made the reduce reads 1152B-strided
// (~16x read amplification) -> 2-level coalesced reduce + 32-way atomics.
// (2) seg was latency-bound (VALUBusy 2%): 1-deep prefetch + 4 tiles/wave has
// no steady state -> R7: 2-tile-deep named-register prefetch, 8 tiles/wave,
// 1024 blocks all co-resident.

typedef __attribute__((ext_vector_type(8)))  short short8;
typedef __attribute__((ext_vector_type(16))) float f32x16;

constexpr int NSEGF  = 32;            // segments 1..32 (label 0 = background, dropped)
constexpr int RPS    = 9;             // 8 channels + count
constexpr int NROWS  = NSEGF * RPS;   // 288 reduced rows
constexpr int BLK    = 256;
constexpr int WPB    = 4;             // waves per block
constexpr int NBLK   = 1024;
constexpr int NWAVE  = NBLK * WPB;    // 4096 waves
constexpr int TILE   = 128;           // pixels per wave-tile = 8 MFMA k-steps
constexpr int KSTEPS = TILE / 16;     // 8
constexpr int PPAD   = 136;           // padded bf16 px per channel row (272B)
constexpr int R1BLK  = 32;            // level-1 reduce blocks
constexpr int SLABS  = NBLK / R1BLK;  // 32 slabs per reduce block
constexpr int PARTBASE = 512;         // ws float offset of per-block partials

__device__ __forceinline__ unsigned pkbf(float a, float b) {
  const unsigned lo = (unsigned)__bfloat16_as_ushort(__float2bfloat16(a));
  const unsigned hi = (unsigned)__bfloat16_as_ushort(__float2bfloat16(b));
  return lo | (hi << 16);
}

__device__ __forceinline__ f32x16 compute_tile(const unsigned short* __restrict__ pbuf,
                                               const int* __restrict__ lbuf,
                                               int col, int hi, int myseg,
                                               short8 Bconst, f32x16 acc) {
  const int bcol = col & 7;   // clamped LDS row so inactive lanes read in-bounds
#pragma unroll
  for (int t = 0; t < KSTEPS; ++t) {
    const int4 la = *(const int4*)&lbuf[t * 16 + hi * 8];
    const int4 lc = *(const int4*)&lbuf[t * 16 + hi * 8 + 4];
    short8 A;
    const short one = (short)0x3F80;
    A[0] = (la.x == myseg) ? one : (short)0;
    A[1] = (la.y == myseg) ? one : (short)0;
    A[2] = (la.z == myseg) ? one : (short)0;
    A[3] = (la.w == myseg) ? one : (short)0;
    A[4] = (lc.x == myseg) ? one : (short)0;
    A[5] = (lc.y == myseg) ? one : (short)0;
    A[6] = (lc.z == myseg) ? one : (short)0;
    A[7] = (lc.w == myseg) ? one : (short)0;

    const short8 Bl = *(const short8*)&pbuf[bcol * PPAD + t * 16 + hi * 8];
    const short8 B  = (col < 8) ? Bl : Bconst;
    acc = __builtin_amdgcn_mfma_f32_32x32x16_bf16(A, B, acc, 0, 0, 0);
  }
  return acc;
}

#define LOADSET(r0, r1, r2, r3, rl, t)                          \
  {                                                             \
    const float* s_ = sbase + (size_t)(t) * TILE;               \
    r0 = *(const float4*)(s_);                                  \
    r1 = *(const float4*)(s_ + 4);                              \
    r2 = *(const float4*)(s_ + 8);                              \
    r3 = *(const float4*)(s_ + 12);                             \
    rl = *(const int2*)&lab[(size_t)(t) * TILE + lane * 2];     \
  }

#define WRITESET(buf, r0, r1, r2, r3, rl)                                          \
  {                                                                                \
    *(int4*)&predL[wid][buf][sc][spc] =                                            \
        make_int4((int)pkbf(r0.x, r0.y), (int)pkbf(r0.z, r0.w),                    \
                  (int)pkbf(r1.x, r1.y), (int)pkbf(r1.z, r1.w));                   \
    *(int4*)&predL[wid][buf][sc][spc + 8] =                                        \
        make_int4((int)pkbf(r2.x, r2.y), (int)pkbf(r2.z, r2.w),                    \
                  (int)pkbf(r3.x, r3.y), (int)pkbf(r3.z, r3.w));                   \
    *(int2*)&labL[wid][buf][lane * 2] = rl;                                        \
  }

__global__ __launch_bounds__(BLK, 4)
void seg_mfma(const float* __restrict__ pred,
              const int*   __restrict__ lab,
              float*       __restrict__ ws,
              int P) {
  __shared__ __align__(16) unsigned short predL[WPB][2][8][PPAD];  // bf16 bits
  __shared__ __align__(16) int            labL[WPB][2][TILE];
  __shared__ float red[WPB][NROWS];

  const int tid   = threadIdx.x;
  const int wid   = tid >> 6;
  const int lane  = tid & 63;
  const int col   = lane & 31;   // D col: 0..7 channel, 8 count, 9..31 unused
  const int hi    = lane >> 5;   // k-half
  const int myseg = col + 1;     // A row 'col' accumulates segment col+1

  const int ntiles = P / TILE;   // fast path requires P % TILE == 0
  const int gw     = blockIdx.x * WPB + wid;

  const int sc  = lane >> 3;            // staged channel
  const int spc = (lane & 7) * 16;      // staged px offset within tile
  const float* sbase = pred + (size_t)sc * P + spc;

  f32x16 acc;
#pragma unroll
  for (int i = 0; i < 16; ++i) acc[i] = 0.f;

  short8 Bconst;   // col 8 -> bf16 1.0 (counts); other non-channel cols -> 0
  {
    const short v = (col == 8) ? (short)0x3F80 : (short)0;
#pragma unroll
    for (int i = 0; i < 8; ++i) Bconst[i] = v;
  }

  float4 a0, a1, a2, a3; int2 al;   // prefetch set A (even tiles -> LDS buf 0)
  float4 b0, b1, b2, b3; int2 bl;   // prefetch set B (odd tiles  -> LDS buf 1)

  int tc = gw;                 // next tile to compute
  int tl = gw + 2 * NWAVE;     // next tile to load (2-deep)

  if (tc < ntiles)         LOADSET(a0, a1, a2, a3, al, tc);
  if (tc + NWAVE < ntiles) LOADSET(b0, b1, b2, b3, bl, tc + NWAVE);
  if (tc < ntiles)         WRITESET(0, a0, a1, a2, a3, al);

  while (tc < ntiles) {
    // body A: compute buf0 (tile tc); write buf1 from set B; refill set A
    if (tl < ntiles) LOADSET(a0, a1, a2, a3, al, tl);
    acc = compute_tile(&predL[wid][0][0][0], labL[wid][0], col, hi, myseg, Bconst, acc);
    if (tc + NWAVE < ntiles) WRITESET(1, b0, b1, b2, b3, bl);
    tc += NWAVE; tl += NWAVE;
    if (tc >= ntiles) break;

    // body B: compute buf1; write buf0 from set A; refill set B
    if (tl < ntiles) LOADSET(b0, b1, b2, b3, bl, tl);
    acc = compute_tile(&predL[wid][1][0][0], labL[wid][1], col, hi, myseg, Bconst, acc);
    if (tc + NWAVE < ntiles) WRITESET(0, a0, a1, a2, a3, al);
    tc += NWAVE; tl += NWAVE;
  }

  // D layout (m74/m101-verified, confirmed R4-R6): col=lane&31,
  // row=(reg&3)+8*(reg>>2)+4*(lane>>5); segment = row+1.
  if (col < RPS) {
#pragma unroll
    for (int r = 0; r < 16; ++r) {
      const int row = (r & 3) + 8 * (r >> 2) + 4 * hi;
      red[wid][row * RPS + col] = acc[r];
    }
  }
  __syncthreads();
  for (int v = tid; v < NROWS; v += BLK) {
    float s = 0.f;
#pragma unroll
    for (int w = 0; w < WPB; ++w) s += red[w][v];
    ws[PARTBASE + (size_t)blockIdx.x * NROWS + v] = s;   // contiguous slab
  }
}

// Level-1 reduce: block b sums SLABS contiguous slabs (coalesced), then 32-way
// atomics into the 288 final rows (zeroed by memset each call).
__global__ __launch_bounds__(256)
void reduce1(float* __restrict__ ws) {
  const int b = blockIdx.x;
  for (int v = threadIdx.x; v < NROWS; v += 256) {
    float s = 0.f;
#pragma unroll 4
    for (int i = 0; i < SLABS; ++i)
      s += ws[PARTBASE + (size_t)(b * SLABS + i) * NROWS + v];
    unsafeAtomicAdd(&ws[v], s);
  }
}

// Fallback (C != 8 or P % TILE != 0 or tiny ws): LDS-atomic path, same layout.
__global__ __launch_bounds__(BLK)
void seg_gen(const float* __restrict__ pred,
             const int*   __restrict__ lab,
             float*       __restrict__ ws,
             int P, int C) {
  __shared__ float bins[(NSEGF + 1) * RPS];
  const int tid = threadIdx.x;
  for (int i = tid; i < (NSEGF + 1) * RPS; i += BLK) bins[i] = 0.f;
  __syncthreads();
  const int stride = gridDim.x * BLK;
  const int Cc = C < 8 ? C : 8;
  for (int p = blockIdx.x * BLK + tid; p < P; p += stride) {
    int lb = lab[p]; if (lb < 0) lb = 0; if (lb > NSEGF) lb = NSEGF;
    const int o = lb * RPS;
    unsafeAtomicAdd(&bins[o + 8], 1.f);
    for (int c = 0; c < Cc; ++c)
      unsafeAtomicAdd(&bins[o + c], pred[(size_t)c * P + p]);
  }
  __syncthreads();
  for (int i = tid; i < NSEGF * RPS; i += BLK) {
    const float v = bins[RPS + i];   // segments 1..32 -> rows (k-1)*RPS + c
    if (v != 0.f) unsafeAtomicAdd(&ws[i], v);
  }
}

__global__ __launch_bounds__(64)
void finish_kernel(const float* __restrict__ ws,
                   const int*   __restrict__ nkp,
                   float*       __restrict__ out,
                   int C) {
  __shared__ float sA[NSEGF + 1];
  int K = *nkp; if (K > NSEGF) K = NSEGF;
  const int tid = threadIdx.x;
  const int Cc = C < 8 ? C : 8;
  for (int k = tid; k <= NSEGF; k += 64) sA[k] = 0.f;
  __syncthreads();
  for (int k = 1 + tid; k <= K; k += 64) {
    float s2 = 0.f;
    for (int c = 0; c < Cc; ++c) {
      const float v = ws[(k - 1) * RPS + c];
      s2 = fmaf(v, v, s2);
    }
    sA[k] = ws[(k - 1) * RPS + 8] * s2;
  }
  __syncthreads();

  // All-lane pair loop (R5 lesson: one-lane-at-a-time guard = 90us serial).
  const int npairs = K * (K - 1) / 2;
  float accv = 0.f;
  for (int idx = tid; idx < npairs; idx += 64) {
    int i = 1, rem = idx;
    while (rem >= K - i) { rem -= K - i; ++i; }
    const int j = i + 1 + rem;
    const float ps = sA[i] + sA[j];
    const float d  = fmaxf(3.0f - sqrtf(ps), 0.f);
    accv += logf(fmaf(d, d, 1.f));
  }
#pragma unroll
  for (int off = 32; off > 0; off >>= 1) accv += __shfl_down(accv, off);
  if (tid == 0) out[0] = accv * (float)(K - 1) / (float)K;
}

extern "C" void kernel_launch(void* const* d_in, const int* in_sizes, int n_in,
                              void* d_out, int out_size, void* d_ws, size_t ws_size,
                              hipStream_t stream) {
  const float* pred = (const float*)d_in[0];
  const int*   lab  = (const int*)d_in[2];
  const int*   nkp  = (const int*)d_in[3];
  float*       out  = (float*)d_out;
  float*       ws   = (float*)d_ws;

  const int P = in_sizes[2];        // H*W
  const int C = in_sizes[0] / P;    // channels

  const size_t need = (size_t)(PARTBASE + (size_t)NBLK * NROWS) * sizeof(float);
  const bool fast = (C == 8) && (P % TILE) == 0 && ws_size >= need;

  // Final rows are atomically accumulated (reduce1 / seg_gen) -> re-zero.
  hipMemsetAsync(d_ws, 0, NROWS * sizeof(float), stream);

  if (fast) {
    seg_mfma<<<NBLK, BLK, 0, stream>>>(pred, lab, ws, P);
    reduce1<<<R1BLK, 256, 0, stream>>>(ws);
  } else {
    seg_gen<<<1024, BLK, 0, stream>>>(pred, lab, ws, P, C);
  }
  finish_kernel<<<1, 64, 0, stream>>>(ws, nkp, out, C);
}